// Round 2
// baseline (938.442 us; speedup 1.0000x reference)
//
#include <hip/hip_runtime.h>

typedef unsigned short ushort_t;
typedef unsigned int uint_t;

#define NPTS 50000
#define KNB  16
#define DIM  64
#define BLK  128
#define PPB  (BLK / KNB)      // 8 points per block
#define PITCH 97              // 64 fp32 nf + 32 beta bf16-pairs + 1 pad; 97%32==1 -> conflict-free

__device__ __forceinline__ ushort_t f2bf(float f) {
    uint_t u = __float_as_uint(f);
    u += 0x7fffu + ((u >> 16) & 1u);   // RNE
    return (ushort_t)(u >> 16);
}
__device__ __forceinline__ float bfhi(uint_t u) { return __uint_as_float(u & 0xffff0000u); }
__device__ __forceinline__ float bflo(uint_t u) { return __uint_as_float(u << 16); }

// ws float layout (all fp32)
#define WS_WPHI 0
#define WS_WPSI 4096
#define WS_WA   8192
#define WS_WG   12288
#define WS_WC   16384   // 3*64: W_d1 @ W_d2 folded
#define WS_BC   16576   // 64:   b_d1 @ W_d2 + b_d2
#define WS_BPHI 16640
#define WS_BPSI 16704
#define WS_BA   16768
#define WS_BG   16832

__global__ void pt_prep(const float* __restrict__ Wphi, const float* __restrict__ bphi,
                        const float* __restrict__ Wpsi, const float* __restrict__ bpsi,
                        const float* __restrict__ Wa,   const float* __restrict__ ba,
                        const float* __restrict__ Wg,   const float* __restrict__ bg,
                        const float* __restrict__ Wd1,  const float* __restrict__ bd1,
                        const float* __restrict__ Wd2,  const float* __restrict__ bd2,
                        float* __restrict__ ws) {
    int t = threadIdx.x;
    for (int i = t; i < 4096; i += 256) {
        ws[WS_WPHI + i] = Wphi[i];
        ws[WS_WPSI + i] = Wpsi[i];
        ws[WS_WA + i]   = Wa[i];
        ws[WS_WG + i]   = Wg[i];
    }
    if (t < DIM) {
        ws[WS_BPHI + t] = bphi[t];
        ws[WS_BPSI + t] = bpsi[t];
        ws[WS_BA + t]   = ba[t];
        ws[WS_BG + t]   = bg[t];
        for (int c = 0; c < 3; ++c) {
            float acc = 0.f;
            for (int m = 0; m < DIM; ++m)
                acc += Wd1[c*DIM + m] * Wd2[m*DIM + t];
            ws[WS_WC + c*DIM + t] = acc;
        }
        float acc = bd2[t];
        for (int m = 0; m < DIM; ++m)
            acc += bd1[m] * Wd2[m*DIM + t];
        ws[WS_BC + t] = acc;
    }
}

__global__ __launch_bounds__(BLK, 2)
void pt_main(const float* __restrict__ pxyz,  const float* __restrict__ pfeat,
             const float* __restrict__ nxyz,  const float* __restrict__ nfeat,
             const float* __restrict__ ws,    float* __restrict__ out) {
    __shared__ float phi_s[PPB * 65];
    __shared__ float arena[BLK * PITCH];

    const int t  = threadIdx.x;
    const int n0 = blockIdx.x * PPB;

    const float* __restrict__ fWphi = ws + WS_WPHI;
    const float* __restrict__ fWpsi = ws + WS_WPSI;
    const float* __restrict__ fWa   = ws + WS_WA;
    const float* __restrict__ fWg   = ws + WS_WG;
    const float* __restrict__ fWc   = ws + WS_WC;
    const float* __restrict__ fbc   = ws + WS_BC;
    const float* __restrict__ fbphi = ws + WS_BPHI;
    const float* __restrict__ fbpsi = ws + WS_BPSI;
    const float* __restrict__ fba   = ws + WS_BA;
    const float* __restrict__ fbg   = ws + WS_BG;

    // ---- phi = pf @ W_phi + b_phi for the block's points (cooperative) ----
    #pragma unroll
    for (int i = 0; i < (PPB*DIM)/BLK; ++i) {
        int cell = t + BLK*i;
        int nl = cell >> 6, d = cell & 63;
        size_t base = (size_t)(n0 + nl) * DIM;
        float acc = fbphi[d];
        for (int c = 0; c < DIM; ++c)
            acc += pfeat[base + c] * fWphi[c*DIM + d];
        phi_s[nl*65 + d] = acc;
    }
    __syncthreads();

    const int nl = t >> 4;
    const int kk = t & 15;
    const int n  = n0 + nl;
    const size_t pair = (size_t)n * KNB + kk;

    // per-thread arena row: [0,64) fp32 nf (later reused for fp32 contrib),
    //                       [64,96) beta as packed bf16 pairs, [96] pad
    float*  nfRow    = arena + t * PITCH;
    uint_t* betaRow  = (uint_t*)(nfRow + DIM);

    {
        const float4* src = (const float4*)(nfeat + pair * DIM);
        #pragma unroll
        for (int j = 0; j < 16; ++j) {
            float4 v = src[j];
            nfRow[j*4+0] = v.x; nfRow[j*4+1] = v.y;
            nfRow[j*4+2] = v.z; nfRow[j*4+3] = v.w;
        }
    }

    const float dx = pxyz[(size_t)n*3+0] - nxyz[pair*3+0];
    const float dy = pxyz[(size_t)n*3+1] - nxyz[pair*3+1];
    const float dz = pxyz[(size_t)n*3+2] - nxyz[pair*3+2];

    const float* phiRow = phi_s + nl*65;
    float alpha[DIM];
    float gamma[DIM];

    // ---- stage 2: psi & alpha (fused, one pass over nf), delta, beta ----
    #pragma unroll
    for (int d0 = 0; d0 < DIM; d0 += 8) {
        float pacc[8], aacc[8];
        #pragma unroll
        for (int j = 0; j < 8; ++j) { pacc[j] = 0.f; aacc[j] = 0.f; }
        #pragma unroll 4
        for (int c = 0; c < DIM; ++c) {
            float x = nfRow[c];
            #pragma unroll
            for (int j = 0; j < 8; ++j) {
                pacc[j] += x * fWpsi[c*DIM + d0 + j];
                aacc[j] += x * fWa  [c*DIM + d0 + j];
            }
        }
        #pragma unroll
        for (int j = 0; j < 8; j += 2) {
            int d = d0 + j;
            float del0 = fmaxf(dx*fWc[d]   + dy*fWc[DIM+d]   + dz*fWc[2*DIM+d]   + fbc[d],   0.f);
            float del1 = fmaxf(dx*fWc[d+1] + dy*fWc[DIM+d+1] + dz*fWc[2*DIM+d+1] + fbc[d+1], 0.f);
            float b0 = phiRow[d]   - (pacc[j]   + fbpsi[d])   + del0;
            float b1 = phiRow[d+1] - (pacc[j+1] + fbpsi[d+1]) + del1;
            alpha[d]   = aacc[j]   + fba[d]   + del0;
            alpha[d+1] = aacc[j+1] + fba[d+1] + del1;
            betaRow[j >> 1] = (uint_t)f2bf(b0) | ((uint_t)f2bf(b1) << 16);
        }
        betaRow += 4;   // advance 4 packed words per 8-d chunk
    }
    betaRow = (uint_t*)(nfRow + DIM);

    // ---- stage 3: gamma = beta @ W_gamma + b_gamma ----
    #pragma unroll
    for (int d0 = 0; d0 < DIM; d0 += 8) {
        float gacc[8];
        #pragma unroll
        for (int j = 0; j < 8; ++j) gacc[j] = fbg[d0 + j];
        #pragma unroll 4
        for (int c = 0; c < DIM; c += 2) {
            uint_t u = betaRow[c >> 1];
            float x0 = bflo(u);
            float x1 = bfhi(u);
            #pragma unroll
            for (int j = 0; j < 8; ++j) {
                gacc[j] += x0 * fWg[(c  )*DIM + d0 + j];
                gacc[j] += x1 * fWg[(c+1)*DIM + d0 + j];
            }
        }
        #pragma unroll
        for (int j = 0; j < 8; ++j) gamma[d0 + j] = gacc[j];
    }

    // ---- softmax over the 64 features (thread-local) + contrib ----
    float m = gamma[0];
    #pragma unroll
    for (int d = 1; d < DIM; ++d) m = fmaxf(m, gamma[d]);
    float ssum = 0.f;
    #pragma unroll
    for (int d = 0; d < DIM; ++d) { float e = __expf(gamma[d] - m); gamma[d] = e; ssum += e; }
    float inv = 1.0f / ssum;
    #pragma unroll
    for (int d = 0; d < DIM; ++d)
        nfRow[d] = gamma[d] * inv * alpha[d];   // fp32 contrib over dead nf words

    __syncthreads();

    // ---- reduce over k (16 rows) and store fp32 ----
    #pragma unroll
    for (int i = 0; i < (PPB*DIM)/BLK; ++i) {
        int cell = t + BLK*i;
        int pnl = cell >> 6, d = cell & 63;
        float s2 = 0.f;
        #pragma unroll
        for (int k2 = 0; k2 < KNB; ++k2)
            s2 += arena[(pnl*KNB + k2)*PITCH + d];
        out[(size_t)(n0 + pnl)*DIM + d] = s2;
    }
}

extern "C" void kernel_launch(void* const* d_in, const int* in_sizes, int n_in,
                              void* d_out, int out_size, void* d_ws, size_t ws_size,
                              hipStream_t stream) {
    const float* pxyz  = (const float*)d_in[0];
    const float* pfeat = (const float*)d_in[1];
    const float* nxyz  = (const float*)d_in[2];
    const float* nfeat = (const float*)d_in[3];
    const float* Wphi  = (const float*)d_in[4];
    const float* bphi  = (const float*)d_in[5];
    const float* Wpsi  = (const float*)d_in[6];
    const float* bpsi  = (const float*)d_in[7];
    const float* Wa    = (const float*)d_in[8];
    const float* ba    = (const float*)d_in[9];
    const float* Wg    = (const float*)d_in[10];
    const float* bg    = (const float*)d_in[11];
    const float* Wd1   = (const float*)d_in[12];
    const float* bd1   = (const float*)d_in[13];
    const float* Wd2   = (const float*)d_in[14];
    const float* bd2   = (const float*)d_in[15];
    float* ws = (float*)d_ws;

    pt_prep<<<1, 256, 0, stream>>>(Wphi, bphi, Wpsi, bpsi, Wa, ba, Wg, bg,
                                   Wd1, bd1, Wd2, bd2, ws);
    pt_main<<<NPTS/PPB, BLK, 0, stream>>>(pxyz, pfeat, nxyz, nfeat, ws, (float*)d_out);
}

// Round 3
// 381.102 us; speedup vs baseline: 2.4624x; 2.4624x over previous
//
#include <hip/hip_runtime.h>

typedef unsigned int uint_t;
typedef __attribute__((ext_vector_type(8))) short bf16x8;   // MFMA A/B frag (4 VGPRs)
typedef __attribute__((ext_vector_type(4))) float f32x4;    // MFMA C/D frag

#define NPTS 50000
#define DIM  64
#define KNB  16
#define GPW  16                 // points per wave
#define NGROUPS (NPTS / GPW)    // 3125
#define WPB  4                  // waves per block
#define NBLOCKS ((NGROUPS + WPB - 1) / WPB)

// ws layout in 32-bit words
#define WS_WPA   0       // [Wpsi|Walpha] frag-packed bf16: 16 frags * 64 lanes * 4 words
#define WS_WG    4096    // Wgamma frag-packed: 8 * 64 * 4
#define WS_WPHI  6144    // Wphi   frag-packed: 8 * 64 * 4
#define WS_WC    8192    // folded W_d1@W_d2: 3*64 fp32
#define WS_BC    8384    // folded b_d1@W_d2+b_d2: 64
#define WS_BPP   8448    // bphi - bpsi: 64
#define WS_BA    8512    // 64
#define WS_BG    8576    // 64

__device__ __forceinline__ uint_t rne_pack(float a, float b) {
    uint_t ua = __float_as_uint(a); ua += 0x7fffu + ((ua >> 16) & 1u);
    uint_t ub = __float_as_uint(b); ub += 0x7fffu + ((ub >> 16) & 1u);
    return (ua >> 16) | (ub & 0xffff0000u);
}

union Frag { uint_t u[4]; bf16x8 s; uint4 v; };

__global__ void pt_prep(const float* __restrict__ Wphi, const float* __restrict__ bphi,
                        const float* __restrict__ Wpsi, const float* __restrict__ bpsi,
                        const float* __restrict__ Wa,   const float* __restrict__ ba,
                        const float* __restrict__ Wg,   const float* __restrict__ bg,
                        const float* __restrict__ Wd1,  const float* __restrict__ bd1,
                        const float* __restrict__ Wd2,  const float* __restrict__ bd2,
                        float* __restrict__ ws) {
    int t = threadIdx.x;           // 256 threads
    uint_t* wsu = (uint_t*)ws;
    // [Wpsi | Walpha] -> 16 frags (nt 0..7, s 0..1); B[k][n]: n=nt*16+(lane&15), k=s*32+(lane>>4)*8+j
    for (int idx = t; idx < 16*64*4; idx += 256) {
        int w = idx & 3, lane = (idx >> 2) & 63, f = idx >> 8;
        int nt = f >> 1, s = f & 1;
        int k = s*32 + (lane >> 4)*8 + 2*w;
        int col = (nt & 3)*16 + (lane & 15);
        const float* W = (nt < 4) ? Wpsi : Wa;
        wsu[WS_WPA + idx] = rne_pack(W[k*64 + col], W[(k+1)*64 + col]);
    }
    for (int idx = t; idx < 8*64*4; idx += 256) {
        int w = idx & 3, lane = (idx >> 2) & 63, f = idx >> 8;
        int nt = f >> 1, s = f & 1;
        int k = s*32 + (lane >> 4)*8 + 2*w;
        int col = nt*16 + (lane & 15);
        wsu[WS_WG   + idx] = rne_pack(Wg[k*64 + col],   Wg[(k+1)*64 + col]);
        wsu[WS_WPHI + idx] = rne_pack(Wphi[k*64 + col], Wphi[(k+1)*64 + col]);
    }
    if (t < DIM) {
        for (int c = 0; c < 3; ++c) {
            float acc = 0.f;
            for (int m = 0; m < DIM; ++m) acc += Wd1[c*DIM + m] * Wd2[m*DIM + t];
            ws[WS_WC + c*DIM + t] = acc;
        }
        float acc = bd2[t];
        for (int m = 0; m < DIM; ++m) acc += bd1[m] * Wd2[m*DIM + t];
        ws[WS_BC  + t] = acc;
        ws[WS_BPP + t] = bphi[t] - bpsi[t];
        ws[WS_BA  + t] = ba[t];
        ws[WS_BG  + t] = bg[t];
    }
}

#define MFMA(A, B, C) __builtin_amdgcn_mfma_f32_16x16x32_bf16((A), (B), (C), 0, 0, 0)

// per-wave LDS area: phi 16*65 + beta-transpose 64*17 + dxyz 64 = 2192 floats
#define PHI_SZ (16*65)
#define BTR_SZ (64*17)
#define WAREA  (PHI_SZ + BTR_SZ + 64)

__global__ __launch_bounds__(256, 2)
void pt_main(const float* __restrict__ pxyz, const float* __restrict__ pfeat,
             const float* __restrict__ nxyz, const float* __restrict__ nfeat,
             const float* __restrict__ ws,   float* __restrict__ out) {
    __shared__ uint4 wlds[16*64];                 // WG frags [0,512) + WPHI frags [512,1024): 16KB
    __shared__ float warea[WPB][WAREA];           // 35KB

    const int t    = threadIdx.x;
    const int wv   = t >> 6;
    const int lane = t & 63;
    const int c16  = lane & 15;
    const int quad = lane >> 4;

    // stage WG + WPHI frag images to LDS (coalesced), then one-and-only barrier
    {
        const uint4* src = (const uint4*)((const uint_t*)ws + WS_WG);   // WG then WPHI contiguous
        for (int i = t; i < 16*64; i += 256) wlds[i] = src[i];
    }
    __syncthreads();

    const int g = blockIdx.x * WPB + wv;
    if (g >= NGROUPS) return;

    float* phi_s = &warea[wv][0];
    float* btr   = phi_s + PHI_SZ;
    float* dxyz  = btr + BTR_SZ;

    // ---- persistent registers ----
    Frag bpa[16];
    #pragma unroll
    for (int f = 0; f < 16; ++f)
        bpa[f].v = ((const uint4*)((const uint_t*)ws + WS_WPA))[f*64 + lane];

    float wcx[4], wcy[4], wcz[4], wbc[4], bar[4], bgr[4], bppr[4];
    #pragma unroll
    for (int nt = 0; nt < 4; ++nt) {
        int d = nt*16 + c16;
        wcx[nt]  = ws[WS_WC + d];
        wcy[nt]  = ws[WS_WC + 64 + d];
        wcz[nt]  = ws[WS_WC + 128 + d];
        wbc[nt]  = ws[WS_BC + d];
        bppr[nt] = ws[WS_BPP + d];
        bar[nt]  = ws[WS_BA + d];
        bgr[nt]  = ws[WS_BG + d];
    }

    const int g0 = g * GPW;

    // ---- phi for the 16 points of this group (one MFMA pass, M=16 points) ----
    {
        const float* base = pfeat + (size_t)(g0 + c16)*DIM + quad*8;
        float4 x0 = *(const float4*)(base);
        float4 x1 = *(const float4*)(base + 4);
        float4 x2 = *(const float4*)(base + 32);
        float4 x3 = *(const float4*)(base + 36);
        Frag a0, a1;
        a0.u[0] = rne_pack(x0.x, x0.y); a0.u[1] = rne_pack(x0.z, x0.w);
        a0.u[2] = rne_pack(x1.x, x1.y); a0.u[3] = rne_pack(x1.z, x1.w);
        a1.u[0] = rne_pack(x2.x, x2.y); a1.u[1] = rne_pack(x2.z, x2.w);
        a1.u[2] = rne_pack(x3.x, x3.y); a1.u[3] = rne_pack(x3.z, x3.w);
        #pragma unroll
        for (int nt = 0; nt < 4; ++nt) {
            f32x4 acc = {bppr[nt], bppr[nt], bppr[nt], bppr[nt]};   // bphi - bpsi folded in
            Frag b0, b1;
            b0.v = wlds[512 + (nt*2 + 0)*64 + lane];
            b1.v = wlds[512 + (nt*2 + 1)*64 + lane];
            acc = MFMA(a0.s, b0.s, acc);
            acc = MFMA(a1.s, b1.s, acc);
            #pragma unroll
            for (int r = 0; r < 4; ++r)
                phi_s[(quad*4 + r)*65 + nt*16 + c16] = acc[r];
        }
    }

    // ---- software-pipelined loads for pair-step 0 ----
    float4 x0, x1, x2, x3; float nv = 0.f;
    {
        const float* nfb = nfeat + ((size_t)g0*KNB + c16)*DIM + quad*8;
        x0 = *(const float4*)(nfb);
        x1 = *(const float4*)(nfb + 4);
        x2 = *(const float4*)(nfb + 32);
        x3 = *(const float4*)(nfb + 36);
        if (lane < 48) nv = nxyz[(size_t)g0*KNB*3 + lane];
    }

    #pragma unroll 1
    for (int i = 0; i < GPW; ++i) {
        const int n = g0 + i;
        const size_t pbase = (size_t)n * KNB;

        float4 c0 = x0, c1 = x1, c2 = x2, c3 = x3;
        float cnv = nv;

        if (i + 1 < GPW) {   // prefetch next point
            const float* nfb = nfeat + (pbase + KNB + c16)*DIM + quad*8;
            x0 = *(const float4*)(nfb);
            x1 = *(const float4*)(nfb + 4);
            x2 = *(const float4*)(nfb + 32);
            x3 = *(const float4*)(nfb + 36);
            if (lane < 48) nv = nxyz[(pbase + KNB)*3 + lane];
        }

        // dxyz for this point's 16 neighbors
        {
            float p0 = pxyz[n*3], p1 = pxyz[n*3+1], p2 = pxyz[n*3+2];
            if (lane < 48) {
                int pr = lane / 3, comp = lane - pr*3;
                float px = (comp == 0) ? p0 : ((comp == 1) ? p1 : p2);
                dxyz[lane] = px - cnv;
            }
        }

        Frag na0, na1;
        na0.u[0] = rne_pack(c0.x, c0.y); na0.u[1] = rne_pack(c0.z, c0.w);
        na0.u[2] = rne_pack(c1.x, c1.y); na0.u[3] = rne_pack(c1.z, c1.w);
        na1.u[0] = rne_pack(c2.x, c2.y); na1.u[1] = rne_pack(c2.z, c2.w);
        na1.u[2] = rne_pack(c3.x, c3.y); na1.u[3] = rne_pack(c3.z, c3.w);

        // ---- psi (nt 0..3, raw) and alpha (nt 4..7, init ba) ----
        f32x4 acc[8];
        #pragma unroll
        for (int nt = 0; nt < 8; ++nt) {
            float iv = (nt < 4) ? 0.f : bar[nt-4];
            acc[nt] = f32x4{iv, iv, iv, iv};
        }
        #pragma unroll
        for (int nt = 0; nt < 8; ++nt) {
            acc[nt] = MFMA(na0.s, bpa[nt*2 + 0].s, acc[nt]);
            acc[nt] = MFMA(na1.s, bpa[nt*2 + 1].s, acc[nt]);
        }

        // ---- delta, beta (to LDS transposed), alpha finalize ----
        float dx[4], dy[4], dz[4];
        #pragma unroll
        for (int r = 0; r < 4; ++r) {
            int m = quad*4 + r;
            dx[r] = dxyz[m*3]; dy[r] = dxyz[m*3+1]; dz[r] = dxyz[m*3+2];
        }
        float alpha[4][4];
        #pragma unroll
        for (int nt = 0; nt < 4; ++nt) {
            float phv = phi_s[i*65 + nt*16 + c16];   // includes bphi - bpsi
            #pragma unroll
            for (int r = 0; r < 4; ++r) {
                float del = fmaxf(dx[r]*wcx[nt] + dy[r]*wcy[nt] + dz[r]*wcz[nt] + wbc[nt], 0.f);
                float beta = phv - acc[nt][r] + del;
                alpha[nt][r] = acc[nt+4][r] + del;
                btr[(nt*16 + c16)*17 + quad*4 + r] = beta;
            }
        }

        // ---- gamma = beta @ Wg + bg ----
        Frag ga0, ga1;
        #pragma unroll
        for (int w = 0; w < 4; ++w) {
            int j = 2*w;
            float f0 = btr[(quad*8 + j    )*17 + c16];
            float f1 = btr[(quad*8 + j + 1)*17 + c16];
            float f2 = btr[(32 + quad*8 + j    )*17 + c16];
            float f3 = btr[(32 + quad*8 + j + 1)*17 + c16];
            ga0.u[w] = rne_pack(f0, f1);
            ga1.u[w] = rne_pack(f2, f3);
        }
        f32x4 gacc[4];
        #pragma unroll
        for (int nt = 0; nt < 4; ++nt) gacc[nt] = f32x4{bgr[nt], bgr[nt], bgr[nt], bgr[nt]};
        #pragma unroll
        for (int nt = 0; nt < 4; ++nt) {
            Frag b0, b1;
            b0.v = wlds[(nt*2 + 0)*64 + lane];
            b1.v = wlds[(nt*2 + 1)*64 + lane];
            gacc[nt] = MFMA(ga0.s, b0.s, gacc[nt]);
            gacc[nt] = MFMA(ga1.s, b1.s, gacc[nt]);
        }

        // ---- softmax over features, fully in-register (rows = quad*4+r) ----
        float rho[4][4], smi[4];
        #pragma unroll
        for (int r = 0; r < 4; ++r) {
            float mx = fmaxf(fmaxf(gacc[0][r], gacc[1][r]), fmaxf(gacc[2][r], gacc[3][r]));
            #pragma unroll
            for (int d = 1; d < 16; d <<= 1) mx = fmaxf(mx, __shfl_xor(mx, d));
            float s = 0.f;
            #pragma unroll
            for (int nt = 0; nt < 4; ++nt) { float e = __expf(gacc[nt][r] - mx); rho[nt][r] = e; s += e; }
            #pragma unroll
            for (int d = 1; d < 16; d <<= 1) s += __shfl_xor(s, d);
            smi[r] = __builtin_amdgcn_rcpf(s);
        }

        // ---- out[d] = sum_k rho*alpha ----
        float outp[4];
        #pragma unroll
        for (int nt = 0; nt < 4; ++nt) {
            float p = 0.f;
            #pragma unroll
            for (int r = 0; r < 4; ++r) p += rho[nt][r] * smi[r] * alpha[nt][r];
            p += __shfl_xor(p, 16);
            p += __shfl_xor(p, 32);
            outp[nt] = p;
        }
        float sel = (quad == 0) ? outp[0] : (quad == 1) ? outp[1] : (quad == 2) ? outp[2] : outp[3];
        out[(size_t)n*DIM + lane] = sel;   // quad*16+c16 == lane: fully coalesced
    }
}

extern "C" void kernel_launch(void* const* d_in, const int* in_sizes, int n_in,
                              void* d_out, int out_size, void* d_ws, size_t ws_size,
                              hipStream_t stream) {
    const float* pxyz  = (const float*)d_in[0];
    const float* pfeat = (const float*)d_in[1];
    const float* nxyz  = (const float*)d_in[2];
    const float* nfeat = (const float*)d_in[3];
    const float* Wphi  = (const float*)d_in[4];
    const float* bphi  = (const float*)d_in[5];
    const float* Wpsi  = (const float*)d_in[6];
    const float* bpsi  = (const float*)d_in[7];
    const float* Wa    = (const float*)d_in[8];
    const float* ba    = (const float*)d_in[9];
    const float* Wg    = (const float*)d_in[10];
    const float* bg    = (const float*)d_in[11];
    const float* Wd1   = (const float*)d_in[12];
    const float* bd1   = (const float*)d_in[13];
    const float* Wd2   = (const float*)d_in[14];
    const float* bd2   = (const float*)d_in[15];
    float* ws = (float*)d_ws;

    pt_prep<<<1, 256, 0, stream>>>(Wphi, bphi, Wpsi, bpsi, Wa, ba, Wg, bg,
                                   Wd1, bd1, Wd2, bd2, ws);
    pt_main<<<NBLOCKS, 256, 0, stream>>>(pxyz, pfeat, nxyz, nfeat, ws, (float*)d_out);
}

// Round 4
// 347.088 us; speedup vs baseline: 2.7038x; 1.0980x over previous
//
#include <hip/hip_runtime.h>
#include <hip/hip_bf16.h>

typedef unsigned int uint_t;
typedef __attribute__((ext_vector_type(8))) short bf16x8;   // MFMA A/B frag (4 VGPRs)
typedef __attribute__((ext_vector_type(4))) float f32x4;    // MFMA C/D frag

#define NPTS 50000
#define DIM  64
#define KNB  16
#define GPW  8                  // points per wave (one group per wave)
#define NGROUPS (NPTS / GPW)    // 6250
#define WPB  4                  // waves per block
#define NBLOCKS ((NGROUPS + WPB - 1) / WPB)

// ws layout in 32-bit words: frag images are [f*256 + lane*4 + w]
#define FR_WA    0       // Wa frag image (8 frags)
#define FR_PSIG  2048    // -(Wpsi@Wg) frag image
#define FR_WG    4096    // Wg, rows sigma-permuted, frag image
#define FR_PHIG  6144    // (Wphi@Wg) frag image
#define WC4      8192    // 64 x float4 (wcx,wcy,wcz,wbc)
#define GB       8448    // (bphi-bpsi)@Wg + bg
#define BA       8512    // b_alpha

__device__ __forceinline__ uint_t pk(float a, float b) {
    union { __hip_bfloat162 h; uint_t u; } cv;
    cv.h = __float22bfloat162_rn(float2{a, b});
    return cv.u;
}

union Frag { uint_t u[4]; bf16x8 s; uint4 v; };

// sigma: row-permutation of Wg so that the utr writer's in-lane (nt0,nt1)/(nt2,nt3)
// pairs land as the reader's consecutive A-frag k-dim pairs.
__device__ __forceinline__ int sigma(int k) {
    int t = k >> 1;
    return (t & 15) + 32 * (t >> 4) + 16 * (k & 1);
}

__global__ void pt_prep(const float* __restrict__ Wphi, const float* __restrict__ bphi,
                        const float* __restrict__ Wpsi, const float* __restrict__ bpsi,
                        const float* __restrict__ Wa,   const float* __restrict__ ba,
                        const float* __restrict__ Wg,   const float* __restrict__ bg,
                        const float* __restrict__ Wd1,  const float* __restrict__ bd1,
                        const float* __restrict__ Wd2,  const float* __restrict__ bd2,
                        float* __restrict__ ws) {
    int b = blockIdx.x, t = threadIdx.x;
    uint_t* wsu = (uint_t*)ws;
    if (b < 32) {
        int gid  = b * 256 + t;             // [0, 8192)
        int img  = gid >> 11;               // 0..3
        int rem  = gid & 2047;
        int f    = rem >> 8;                // 0..7  (nt = f>>1, s = f&1)
        int lane = (rem >> 2) & 63;
        int w    = rem & 3;
        int k0   = (f & 1) * 32 + (lane >> 4) * 8 + 2 * w;
        int k1   = k0 + 1;
        int n    = (f >> 1) * 16 + (lane & 15);
        float v0, v1;
        if (img == 0) {                     // Wa
            v0 = Wa[k0 * 64 + n]; v1 = Wa[k1 * 64 + n];
            wsu[FR_WA + rem] = pk(v0, v1);
        } else if (img == 1) {              // -(Wpsi@Wg)
            float a0 = 0.f, a1 = 0.f;
            for (int c = 0; c < 64; ++c) {
                float wgc = Wg[c * 64 + n];
                a0 += Wpsi[k0 * 64 + c] * wgc;
                a1 += Wpsi[k1 * 64 + c] * wgc;
            }
            wsu[FR_PSIG + rem] = pk(-a0, -a1);
        } else if (img == 2) {              // Wg sigma-row-permuted
            v0 = Wg[sigma(k0) * 64 + n]; v1 = Wg[sigma(k1) * 64 + n];
            wsu[FR_WG + rem] = pk(v0, v1);
        } else {                            // Wphi@Wg
            float a0 = 0.f, a1 = 0.f;
            for (int c = 0; c < 64; ++c) {
                float wgc = Wg[c * 64 + n];
                a0 += Wphi[k0 * 64 + c] * wgc;
                a1 += Wphi[k1 * 64 + c] * wgc;
            }
            wsu[FR_PHIG + rem] = pk(a0, a1);
        }
    } else if (t < 64) {
        // wc4: folded W_d1@W_d2 (+ folded bias), gb, ba
        float wx = 0.f, wy = 0.f, wz = 0.f;
        for (int m = 0; m < 64; ++m) {
            float w2 = Wd2[m * 64 + t];
            wx += Wd1[m] * w2;
            wy += Wd1[64 + m] * w2;
            wz += Wd1[128 + m] * w2;
        }
        float wb = bd2[t];
        for (int m = 0; m < 64; ++m) wb += bd1[m] * Wd2[m * 64 + t];
        ws[WC4 + t * 4 + 0] = wx;
        ws[WC4 + t * 4 + 1] = wy;
        ws[WC4 + t * 4 + 2] = wz;
        ws[WC4 + t * 4 + 3] = wb;
        float g = bg[t];
        for (int c = 0; c < 64; ++c) g += (bphi[c] - bpsi[c]) * Wg[c * 64 + t];
        ws[GB + t] = g;
        ws[BA + t] = ba[t];
    }
}

#define MFMA(A, B, C) __builtin_amdgcn_mfma_f32_16x16x32_bf16((A), (B), (C), 0, 0, 0)

// per-wave LDS (words): phig 8*65=520 | utr 16*34=544 | dxyz 2*16*4=128 | pxyz 32
#define WAREA 1224

__global__ __launch_bounds__(256, 2)
void pt_main(const float* __restrict__ pxyz, const float* __restrict__ pfeat,
             const float* __restrict__ nxyz, const float* __restrict__ nfeat,
             const float* __restrict__ ws,   float* __restrict__ out) {
    __shared__ float lds[WPB][WAREA];

    const int t    = threadIdx.x;
    const int wv   = t >> 6;
    const int lane = t & 63;
    const int c16  = lane & 15;
    const int quad = lane >> 4;

    const int g = blockIdx.x * WPB + wv;
    if (g >= NGROUPS) return;

    float*  phig_s = &lds[wv][0];
    uint_t* utr    = (uint_t*)(phig_s + 520);
    float*  dxyz   = (float*)(utr + 544);
    float*  pxyz_s = dxyz + 128;

    // ---- persistent weights ----
    const uint4* fr = (const uint4*)ws;       // frag uint4 index = IMG/4 + f*64 + lane
    Frag wa[8], wpsig[8], wg[8];
    #pragma unroll
    for (int f = 0; f < 8; ++f) {
        wa[f].v    = fr[           f * 64 + lane];
        wpsig[f].v = fr[ 512 +     f * 64 + lane];
        wg[f].v    = fr[1024 +     f * 64 + lane];
    }
    float4 wc[4];
    float ba_r[4], gbr[4];
    #pragma unroll
    for (int nt = 0; nt < 4; ++nt) {
        int d = nt * 16 + c16;
        wc[nt]   = ((const float4*)(ws + WC4))[d];
        ba_r[nt] = ws[BA + d];
        gbr[nt]  = ws[GB + d];
    }

    const int g0 = g * GPW;
    const int k3 = lane / 3, c3 = lane - k3 * 3;   // lane<48: (neighbor, component)

    // ---- preamble ----
    if (lane < 24) pxyz_s[lane] = pxyz[g0 * 3 + lane];
    float nv0 = (lane < 48) ? nxyz[(size_t)g0 * 48 + lane] : 0.f;
    if (lane < 48) dxyz[k3 * 4 + c3] = pxyz_s[c3] - nv0;   // point 0, buf 0

    // phig = pf@(Wphi@Wg) + gb for the 8 points (rows 0..7 of one MFMA pass)
    {
        float4 x0{}, x1{}, x2{}, x3{};
        if (c16 < 8) {
            const float* base = pfeat + (size_t)(g0 + c16) * 64 + quad * 8;
            x0 = *(const float4*)(base);
            x1 = *(const float4*)(base + 4);
            x2 = *(const float4*)(base + 32);
            x3 = *(const float4*)(base + 36);
        }
        Frag pa0, pa1;
        pa0.u[0] = pk(x0.x, x0.y); pa0.u[1] = pk(x0.z, x0.w);
        pa0.u[2] = pk(x1.x, x1.y); pa0.u[3] = pk(x1.z, x1.w);
        pa1.u[0] = pk(x2.x, x2.y); pa1.u[1] = pk(x2.z, x2.w);
        pa1.u[2] = pk(x3.x, x3.y); pa1.u[3] = pk(x3.z, x3.w);
        #pragma unroll
        for (int nt = 0; nt < 4; ++nt) {
            Frag b0, b1;
            b0.v = fr[1536 + (nt * 2 + 0) * 64 + lane];
            b1.v = fr[1536 + (nt * 2 + 1) * 64 + lane];
            f32x4 acc = {gbr[nt], gbr[nt], gbr[nt], gbr[nt]};
            acc = MFMA(pa0.s, b0.s, acc);
            acc = MFMA(pa1.s, b1.s, acc);
            if (quad < 2) {
                #pragma unroll
                for (int r = 0; r < 4; ++r)
                    phig_s[(quad * 4 + r) * 65 + nt * 16 + c16] = acc[r];
            }
        }
    }

    // nf prefetch for point 0; nxyz prefetch for point 1
    const float* nfb = nfeat + (size_t)g0 * (KNB * 64) + (size_t)c16 * 64 + quad * 8;
    float4 f0 = *(const float4*)(nfb);
    float4 f1 = *(const float4*)(nfb + 4);
    float4 f2 = *(const float4*)(nfb + 32);
    float4 f3 = *(const float4*)(nfb + 36);
    float nvn = (lane < 48) ? nxyz[(size_t)g0 * 48 + 48 + lane] : 0.f;

    #pragma unroll 1
    for (int i = 0; i < GPW; ++i) {
        const int n = g0 + i;

        // pack current nf A-frags, then overwrite prefetch regs
        Frag na0, na1;
        na0.u[0] = pk(f0.x, f0.y); na0.u[1] = pk(f0.z, f0.w);
        na0.u[2] = pk(f1.x, f1.y); na0.u[3] = pk(f1.z, f1.w);
        na1.u[0] = pk(f2.x, f2.y); na1.u[1] = pk(f2.z, f2.w);
        na1.u[2] = pk(f3.x, f3.y); na1.u[3] = pk(f3.z, f3.w);
        if (i + 1 < GPW) {
            const float* nf2 = nfb + (size_t)(i + 1) * (KNB * 64);
            f0 = *(const float4*)(nf2);
            f1 = *(const float4*)(nf2 + 4);
            f2 = *(const float4*)(nf2 + 32);
            f3 = *(const float4*)(nf2 + 36);
        }

        // early LDS reads: phig values, this point's dxyz rows
        float ph[4];
        #pragma unroll
        for (int nt = 0; nt < 4; ++nt) ph[nt] = phig_s[i * 65 + nt * 16 + c16];
        float4 dd[4];
        #pragma unroll
        for (int r = 0; r < 4; ++r)
            dd[r] = ((const float4*)dxyz)[(i & 1) * 16 + quad * 4 + r];

        // write next point's dxyz (uses prefetched nvn), then prefetch nxyz i+2
        if (i + 1 < GPW) {
            if (lane < 48)
                dxyz[((i + 1) & 1) * 64 + k3 * 4 + c3] = pxyz_s[(i + 1) * 3 + c3] - nvn;
            if (i + 2 < GPW)
                nvn = (lane < 48) ? nxyz[((size_t)n + 2) * 48 + lane] : 0.f;
        }

        // u = diff@Wc + bc, relu -> delta in C-layout; pack transpose into utr
        float d_c[4][4];
        #pragma unroll
        for (int nt = 0; nt < 4; ++nt) {
            #pragma unroll
            for (int r = 0; r < 4; ++r) {
                float u = fmaf(dd[r].x, wc[nt].x,
                          fmaf(dd[r].y, wc[nt].y,
                          fmaf(dd[r].z, wc[nt].z, wc[nt].w)));
                d_c[nt][r] = fmaxf(u, 0.f);
            }
        }
        #pragma unroll
        for (int r = 0; r < 4; ++r) {
            int row = (quad * 4 + r) * 34;
            utr[row + c16]      = pk(d_c[0][r], d_c[1][r]);
            utr[row + 16 + c16] = pk(d_c[2][r], d_c[3][r]);
        }

        // alpha = nf@Wa + ba (delta added after); overlaps utr write latency
        f32x4 aacc[4];
        #pragma unroll
        for (int nt = 0; nt < 4; ++nt) {
            aacc[nt] = f32x4{ba_r[nt], ba_r[nt], ba_r[nt], ba_r[nt]};
            aacc[nt] = MFMA(na0.s, wa[nt * 2 + 0].s, aacc[nt]);
            aacc[nt] = MFMA(na1.s, wa[nt * 2 + 1].s, aacc[nt]);
        }
        // gamma = phig - nf@WpsiG ...
        f32x4 gacc[4];
        #pragma unroll
        for (int nt = 0; nt < 4; ++nt) {
            gacc[nt] = f32x4{ph[nt], ph[nt], ph[nt], ph[nt]};
            gacc[nt] = MFMA(na0.s, wpsig[nt * 2 + 0].s, gacc[nt]);
            gacc[nt] = MFMA(na1.s, wpsig[nt * 2 + 1].s, gacc[nt]);
        }
        // ... + delta@Wg (read back transposed delta as ready-made A-frags)
        Frag da0, da1;
        {
            const uint_t* rowp = utr + c16 * 34 + quad * 4;
            uint2 a = *(const uint2*)(rowp);
            uint2 b = *(const uint2*)(rowp + 2);
            uint2 c = *(const uint2*)(rowp + 16);
            uint2 d = *(const uint2*)(rowp + 18);
            da0.u[0] = a.x; da0.u[1] = a.y; da0.u[2] = b.x; da0.u[3] = b.y;
            da1.u[0] = c.x; da1.u[1] = c.y; da1.u[2] = d.x; da1.u[3] = d.y;
        }
        #pragma unroll
        for (int nt = 0; nt < 4; ++nt) {
            gacc[nt] = MFMA(da0.s, wg[nt * 2 + 0].s, gacc[nt]);
            gacc[nt] = MFMA(da1.s, wg[nt * 2 + 1].s, gacc[nt]);
        }
        // alpha finalize
        #pragma unroll
        for (int nt = 0; nt < 4; ++nt)
            #pragma unroll
            for (int r = 0; r < 4; ++r) aacc[nt][r] += d_c[nt][r];

        // softmax over features (no max-sub: |gamma| small by construction)
        float e[4][4], smi[4];
        #pragma unroll
        for (int r = 0; r < 4; ++r) {
            float s = 0.f;
            #pragma unroll
            for (int nt = 0; nt < 4; ++nt) { e[nt][r] = __expf(gacc[nt][r]); s += e[nt][r]; }
            #pragma unroll
            for (int d2 = 1; d2 < 16; d2 <<= 1) s += __shfl_xor(s, d2);
            smi[r] = __builtin_amdgcn_rcpf(s);
        }
        // out_d = sum_k rho*alpha
        float p0 = 0.f, p1 = 0.f, p2 = 0.f, p3 = 0.f;
        #pragma unroll
        for (int r = 0; r < 4; ++r) {
            p0 = fmaf(e[0][r] * smi[r], aacc[0][r], p0);
            p1 = fmaf(e[1][r] * smi[r], aacc[1][r], p1);
            p2 = fmaf(e[2][r] * smi[r], aacc[2][r], p2);
            p3 = fmaf(e[3][r] * smi[r], aacc[3][r], p3);
        }
        p0 += __shfl_xor(p0, 16); p0 += __shfl_xor(p0, 32);
        p1 += __shfl_xor(p1, 16); p1 += __shfl_xor(p1, 32);
        p2 += __shfl_xor(p2, 16); p2 += __shfl_xor(p2, 32);
        p3 += __shfl_xor(p3, 16); p3 += __shfl_xor(p3, 32);
        float sel = (quad == 0) ? p0 : (quad == 1) ? p1 : (quad == 2) ? p2 : p3;
        out[(size_t)n * 64 + lane] = sel;
    }
}

extern "C" void kernel_launch(void* const* d_in, const int* in_sizes, int n_in,
                              void* d_out, int out_size, void* d_ws, size_t ws_size,
                              hipStream_t stream) {
    const float* pxyz  = (const float*)d_in[0];
    const float* pfeat = (const float*)d_in[1];
    const float* nxyz  = (const float*)d_in[2];
    const float* nfeat = (const float*)d_in[3];
    const float* Wphi  = (const float*)d_in[4];
    const float* bphi  = (const float*)d_in[5];
    const float* Wpsi  = (const float*)d_in[6];
    const float* bpsi  = (const float*)d_in[7];
    const float* Wa    = (const float*)d_in[8];
    const float* ba    = (const float*)d_in[9];
    const float* Wg    = (const float*)d_in[10];
    const float* bg    = (const float*)d_in[11];
    const float* Wd1   = (const float*)d_in[12];
    const float* bd1   = (const float*)d_in[13];
    const float* Wd2   = (const float*)d_in[14];
    const float* bd2   = (const float*)d_in[15];
    float* ws = (float*)d_ws;

    pt_prep<<<33, 256, 0, stream>>>(Wphi, bphi, Wpsi, bpsi, Wa, ba, Wg, bg,
                                    Wd1, bd1, Wd2, bd2, ws);
    pt_main<<<NBLOCKS, 256, 0, stream>>>(pxyz, pfeat, nxyz, nfeat, ws, (float*)d_out);
}